// Round 6
// baseline (507.785 us; speedup 1.0000x reference)
//
#include <hip/hip_runtime.h>
#include <math.h>

#define DIN 3072
#define DF 640
#define MROWS 400
#define QROWS 240
#define NMAT 400
#define PN 416          // padded A dim (13*32, 26*16)
#define NRHS 16
#define CREG 50.0f
#define PVSTEPS 6
#define CSTEPS 27       // Chebyshev: kappa~62 -> q~0.776 -> rel ~2e-3
#define KSPLIT 8        // gemm_feat split-K factor

typedef __attribute__((ext_vector_type(8))) short bf8v;   // 8 bf16 (4 VGPRs)
typedef __attribute__((ext_vector_type(4))) float f32x4;  // MFMA acc

__device__ __forceinline__ short bf16_rn(float x) {
  unsigned u = __float_as_uint(x);
  u += 0x7FFFu + ((u >> 16) & 1u);
  return (short)(u >> 16);
}
__device__ __forceinline__ void split_sh(float x, short& h, short& l) {
  h = bf16_rn(x);
  float hf = __uint_as_float(((unsigned)(unsigned short)h) << 16);
  l = bf16_rn(x - hf);
}
__device__ __forceinline__ float bf2f(short h) {
  return __uint_as_float(((unsigned)(unsigned short)h) << 16);
}

// ---- transpose + split Wb(3072x640) -> Wth,Wtl [640][3072] bf16 -----------
__global__ __launch_bounds__(256) void split_wt(const float* __restrict__ Wb,
                                                short* __restrict__ H,
                                                short* __restrict__ L) {
  __shared__ float T[64][65];
  int n0 = blockIdx.x * 64;   // over DF
  int k0 = blockIdx.y * 64;   // over DIN
  int c = threadIdx.x & 63, r0 = threadIdx.x >> 6;
#pragma unroll
  for (int i = 0; i < 16; ++i) {
    int r = i * 4 + r0;
    T[r][c] = Wb[(size_t)(k0 + r) * DF + n0 + c];
  }
  __syncthreads();
#pragma unroll
  for (int i = 0; i < 16; ++i) {
    int n = i * 4 + r0;
    float x = T[c][n];              // Wb[k0+c][n0+n]
    short h, l; split_sh(x, h, l);
    size_t o = (size_t)(n0 + n) * DIN + k0 + c;
    H[o] = h; L[o] = l;
  }
}

// ---- split-K MFMA GEMM: partial [S;Q] @ Wb -> atomicAdd into Acc(640x640) -
__global__ __launch_bounds__(256) void gemm_feat_sk(const float* __restrict__ S,
                                                    const float* __restrict__ Qm,
                                                    const short* __restrict__ Bh,
                                                    const short* __restrict__ Bl,
                                                    float* __restrict__ Acc) {
  __shared__ float As[64][68];
  __shared__ short Bsh[64][72];
  __shared__ short Bsl[64][72];
  int tid = threadIdx.x;
  int wave = tid >> 6, lane = tid & 63, l16 = lane & 15, quad = lane >> 4;
  int by = blockIdx.y, bx = blockIdx.x, bz = blockIdx.z;
  int colBase = bx * 64;
  int kbeg = bz * (DIN / KSPLIT), kend = kbeg + (DIN / KSPLIT);
  f32x4 acc[4] = {{0,0,0,0},{0,0,0,0},{0,0,0,0},{0,0,0,0}};
  for (int k0 = kbeg; k0 < kend; k0 += 64) {
    __syncthreads();
#pragma unroll
    for (int p = 0; p < 4; ++p) {
      int cid = tid + 256 * p;            // 0..1023
      int row = cid >> 4, kc = cid & 15;
      int arow = by * 64 + row;
      const float* sr = (arow < MROWS) ? (S + (size_t)arow * DIN)
                                       : (Qm + (size_t)(arow - MROWS) * DIN);
      float4 v = *reinterpret_cast<const float4*>(sr + k0 + kc * 4);
      *reinterpret_cast<float4*>(&As[row][kc * 4]) = v;
    }
#pragma unroll
    for (int p = 0; p < 2; ++p) {
      int cid = tid + 256 * p;            // 0..511
      int nn = cid >> 3, kc = cid & 7;
      size_t src = (size_t)(colBase + nn) * DIN + k0 + kc * 8;
      *reinterpret_cast<bf8v*>(&Bsh[nn][kc * 8]) = *reinterpret_cast<const bf8v*>(Bh + src);
      *reinterpret_cast<bf8v*>(&Bsl[nn][kc * 8]) = *reinterpret_cast<const bf8v*>(Bl + src);
    }
    __syncthreads();
#pragma unroll
    for (int kk = 0; kk < 64; kk += 32) {
      int ko = kk + quad * 8;
      float4 a0 = *reinterpret_cast<const float4*>(&As[wave * 16 + l16][ko]);
      float4 a1 = *reinterpret_cast<const float4*>(&As[wave * 16 + l16][ko + 4]);
      float av[8] = {a0.x, a0.y, a0.z, a0.w, a1.x, a1.y, a1.z, a1.w};
      bf8v ah, al;
#pragma unroll
      for (int j = 0; j < 8; ++j) { short h, l; split_sh(av[j], h, l); ah[j] = h; al[j] = l; }
#pragma unroll
      for (int t = 0; t < 4; ++t) {
        bf8v bh = *reinterpret_cast<const bf8v*>(&Bsh[t * 16 + l16][ko]);
        bf8v bl = *reinterpret_cast<const bf8v*>(&Bsl[t * 16 + l16][ko]);
        acc[t] = __builtin_amdgcn_mfma_f32_16x16x32_bf16(ah, bh, acc[t], 0, 0, 0);
        acc[t] = __builtin_amdgcn_mfma_f32_16x16x32_bf16(ah, bl, acc[t], 0, 0, 0);
        acc[t] = __builtin_amdgcn_mfma_f32_16x16x32_bf16(al, bh, acc[t], 0, 0, 0);
      }
    }
  }
  int row0 = by * 64 + wave * 16;
#pragma unroll
  for (int t = 0; t < 4; ++t) {
#pragma unroll
    for (int r = 0; r < 4; ++r) {
      int row = row0 + quad * 4 + r;
      int col = colBase + t * 16 + l16;
      atomicAdd(&Acc[(size_t)row * DF + col], acc[t][r]);
    }
  }
}

// ---- finalize: Acc -> Kh,Kl (rows<400) / FX (rows>=400) -------------------
__global__ __launch_bounds__(256) void finalize_feat(const float* __restrict__ Acc,
                                                     short* __restrict__ Kh,
                                                     short* __restrict__ Kl,
                                                     float* __restrict__ FX) {
  int idx = blockIdx.x * 256 + threadIdx.x;   // < 640*640
  if (idx >= 640 * DF) return;
  float v = Acc[idx];
  int row = idx / DF, col = idx - row * DF;
  if (row < MROWS) {
    short h, l; split_sh(v, h, l);
    Kh[(size_t)row * DF + col] = h;
    Kl[(size_t)row * DF + col] = l;
  } else {
    FX[(size_t)(row - MROWS) * DF + col] = v;
  }
}

// ---- MFMA: A(416x416) = K K^T + 50 I (zero-padded), bf16 hi/lo out --------
__global__ __launch_bounds__(256) void gemm_aul(const short* __restrict__ Kh,
                                                const short* __restrict__ Kl,
                                                short* __restrict__ Aph,
                                                short* __restrict__ Apl) {
  int tid = threadIdx.x;
  int wave = tid >> 6, lane = tid & 63;
  int l16 = lane & 15, quad = lane >> 4;
  int row0 = blockIdx.y * 64 + wave * 16;
  int colBase = blockIdx.x * 64;
  bool aValid = (row0 < MROWS);
  const bf8v bzero = {0,0,0,0,0,0,0,0};
  f32x4 acc[4] = {{0,0,0,0},{0,0,0,0},{0,0,0,0},{0,0,0,0}};
  for (int k0 = 0; k0 < DF; k0 += 32) {
    int ka = k0 + quad * 8;
    bf8v ah = bzero, al = bzero;
    if (aValid) {
      size_t ao = (size_t)(row0 + l16) * DF + ka;
      ah = *reinterpret_cast<const bf8v*>(Kh + ao);
      al = *reinterpret_cast<const bf8v*>(Kl + ao);
    }
#pragma unroll
    for (int t = 0; t < 4; ++t) {
      int colt = colBase + t * 16;
      bf8v bh = bzero, bl = bzero;
      if (colt < MROWS) {
        size_t bo = (size_t)(colt + l16) * DF + ka;
        bh = *reinterpret_cast<const bf8v*>(Kh + bo);
        bl = *reinterpret_cast<const bf8v*>(Kl + bo);
      }
      acc[t] = __builtin_amdgcn_mfma_f32_16x16x32_bf16(ah, bh, acc[t], 0, 0, 0);
      acc[t] = __builtin_amdgcn_mfma_f32_16x16x32_bf16(ah, bl, acc[t], 0, 0, 0);
      acc[t] = __builtin_amdgcn_mfma_f32_16x16x32_bf16(al, bh, acc[t], 0, 0, 0);
    }
  }
  if (row0 >= PN) return;
#pragma unroll
  for (int t = 0; t < 4; ++t) {
    int colt = colBase + t * 16;
    if (colt >= PN) continue;
#pragma unroll
    for (int r = 0; r < 4; ++r) {
      int row = row0 + quad * 4 + r;
      int col = colt + l16;
      float v = acc[t][r];
      if (row == col && row < MROWS) v += CREG;
      short h, l; split_sh(v, h, l);
      size_t o = (size_t)row * PN + col;
      Aph[o] = h; Apl[o] = l;
    }
  }
}

// ---- single-block replicated solve: PV (lambda_max) + Chebyshev on A X = P
// One CU; A (bf16 hi/lo) streams from L2 every step (~4.4us floor); matvec
// via MFMA; d iterate in LDS; r,x in registers. NO grid barriers/fences.
__global__ __launch_bounds__(512) void solve_rep(const short* __restrict__ Ah,
                                                 const short* __restrict__ Al,
                                                 float* __restrict__ X) {
  __shared__ float d[16][PN + 1];        // fp32 iterate, [c][j]
  __shared__ short dh[16][PN + 8];       // bf16 hi (B-operand layout)
  __shared__ short dl[16][PN + 8];       // bf16 lo
  __shared__ float mv[PN][17];           // matvec out, [i][c]
  __shared__ float scal[2];
  int tid = threadIdx.x;
  int c = tid & 15, q = tid >> 4;        // q 0..31
  int wave = tid >> 6, lane = tid & 63, l16 = lane & 15, quad = lane >> 4;

  // ---- init PV vector in dh[0], zeros elsewhere ----
  for (int e = tid; e < PN; e += 512) {
    dh[0][e] = bf16_rn((e < NMAT) ? (1.f + 0.125f * (float)(e & 7)) : 0.f);
#pragma unroll
    for (int cc = 1; cc < 16; ++cc) dh[cc][e] = 0;
  }
  __syncthreads();

  // ---- power iteration: 6 steps, Ah-only MFMA matvec on column 0 ----
  for (int s = 0; s < PVSTEPS; ++s) {
    f32x4 acc[4] = {{0,0,0,0},{0,0,0,0},{0,0,0,0},{0,0,0,0}};
    for (int kc = 0; kc < 13; ++kc) {
      int jb = 32 * kc + quad * 8;
      bf8v bh = *reinterpret_cast<const bf8v*>(&dh[l16][jb]);
#pragma unroll
      for (int tt = 0; tt < 4; ++tt) {
        int t = wave + 8 * tt;
        if (t < 26) {
          bf8v ah = *reinterpret_cast<const bf8v*>(Ah + (size_t)(t * 16 + l16) * PN + jb);
          acc[tt] = __builtin_amdgcn_mfma_f32_16x16x32_bf16(ah, bh, acc[tt], 0, 0, 0);
        }
      }
    }
#pragma unroll
    for (int tt = 0; tt < 4; ++tt) {
      int t = wave + 8 * tt;
      if (t < 26)
#pragma unroll
        for (int r = 0; r < 4; ++r) mv[t * 16 + quad * 4 + r][l16] = acc[tt][r];
    }
    __syncthreads();
    for (int e = tid; e < PN; e += 512) {
      dh[1][e] = dh[0][e];                         // prev
      dh[0][e] = bf16_rn(mv[e][0] * (1.f / 4096.f));  // cur
    }
    __syncthreads();
  }
  // ---- Rayleigh quotient: rq = 4096 * (vprev.vcur)/(vprev.vprev) ----
  if (tid < 32) {
    float n = 0.f, dd = 0.f;
    for (int m = 0; m < 13; ++m) {
      int i = tid + 32 * m;
      float vp = bf2f(dh[1][i]), vl = bf2f(dh[0][i]);
      n += vp * vl; dd += vp * vp;
    }
    mv[tid][0] = n; mv[tid][1] = dd;
  }
  __syncthreads();
  if (tid == 0) {
    float n = 0.f, dd = 0.f;
    for (int u = 0; u < 32; ++u) { n += mv[u][0]; dd += mv[u][1]; }
    float rqv = 4096.f * n / dd;
    float b = 1.25f * rqv;
    if (!(b > 800.f)) b = 12000.f;     // degenerate/NaN fallback
    if (b > 100000.f) b = 100000.f;
    scal[0] = b;
  }
  __syncthreads();
  float bnd = scal[0];
  float theta = 0.5f * (bnd + CREG), delta = 0.5f * (bnd - CREG);
  float sigma = theta / delta, rho = 1.f / sigma;

  // ---- Chebyshev init: thread (c,q) owns rows i=q+32m ----
  float xr[13], rr[13];
#pragma unroll
  for (int m = 0; m < 13; ++m) {
    int i = q + 32 * m;
    float pc = (i < NMAT && (i / 25) == c) ? 1.f : 0.f;
    xr[m] = 0.f; rr[m] = pc;
    float dv = pc / theta;
    d[c][i] = dv;
    short h, l; split_sh(dv, h, l);
    dh[c][i] = h; dl[c][i] = l;
  }
  __syncthreads();

  // ---- Chebyshev steps (Saad Alg 12.1) ----
  for (int k = 0; k < CSTEPS; ++k) {
    f32x4 acc[4] = {{0,0,0,0},{0,0,0,0},{0,0,0,0},{0,0,0,0}};
    for (int kc = 0; kc < 13; ++kc) {
      int jb = 32 * kc + quad * 8;
      bf8v bh = *reinterpret_cast<const bf8v*>(&dh[l16][jb]);
      bf8v bl = *reinterpret_cast<const bf8v*>(&dl[l16][jb]);
#pragma unroll
      for (int tt = 0; tt < 4; ++tt) {
        int t = wave + 8 * tt;
        if (t < 26) {
          size_t ao = (size_t)(t * 16 + l16) * PN + jb;
          bf8v ah = *reinterpret_cast<const bf8v*>(Ah + ao);
          bf8v al = *reinterpret_cast<const bf8v*>(Al + ao);
          acc[tt] = __builtin_amdgcn_mfma_f32_16x16x32_bf16(ah, bh, acc[tt], 0, 0, 0);
          acc[tt] = __builtin_amdgcn_mfma_f32_16x16x32_bf16(ah, bl, acc[tt], 0, 0, 0);
          acc[tt] = __builtin_amdgcn_mfma_f32_16x16x32_bf16(al, bh, acc[tt], 0, 0, 0);
        }
      }
    }
#pragma unroll
    for (int tt = 0; tt < 4; ++tt) {
      int t = wave + 8 * tt;
      if (t < 26)
#pragma unroll
        for (int r = 0; r < 4; ++r) mv[t * 16 + quad * 4 + r][l16] = acc[tt][r];
    }
    __syncthreads();
    float rho1 = 1.f / (2.f * sigma - rho);
    float s1 = rho1 * rho, s2 = 2.f * rho1 / delta;
    rho = rho1;
#pragma unroll
    for (int m = 0; m < 13; ++m) {
      int i = q + 32 * m;
      float dv = d[c][i];
      xr[m] += dv;
      rr[m] -= mv[i][c];
      float dn = s1 * dv + s2 * rr[m];
      d[c][i] = dn;
      short h, l; split_sh(dn, h, l);
      dh[c][i] = h; dl[c][i] = l;
    }
    __syncthreads();
  }
#pragma unroll
  for (int m = 0; m < 13; ++m) {
    int i = q + 32 * m;
    if (i < NMAT) X[i * NRHS + c] = xr[m];
  }
}

// ---- WK[j][d] = sum_i X[i][j] K[i][d], K = Kh+Kl --------------------------
__global__ __launch_bounds__(256) void wk_kernel(const float* __restrict__ X,
                                                 const short* __restrict__ Kh,
                                                 const short* __restrict__ Kl,
                                                 float* __restrict__ WK) {
  int idx = blockIdx.x * 256 + threadIdx.x;   // < 16*640
  int j = idx / DF;
  int d = idx - j * DF;
  float acc = 0.f;
  for (int i = 0; i < NMAT; ++i) {
    float kv = bf2f(Kh[(size_t)i * DF + d]) + bf2f(Kl[(size_t)i * DF + d]);
    acc += X[i * NRHS + j] * kv;
  }
  WK[idx] = acc;
}

// ---- logits[q][c] = -gamma * dot(FX[q], WK[c]) ----------------------------
__global__ __launch_bounds__(256) void logits_kernel(const float* __restrict__ FX,
                                                     const float* __restrict__ WK,
                                                     const float* __restrict__ gamma,
                                                     float* __restrict__ out) {
  int idx = blockIdx.x * 256 + threadIdx.x;
  int q = idx >> 4, c = idx & 15;
  const float* fr = FX + (size_t)q * DF;
  const float* wr = WK + (size_t)c * DF;
  float acc = 0.f;
  for (int d = 0; d < DF; ++d) acc += fr[d] * wr[d];
  out[idx] = -gamma[0] * acc;
}

extern "C" void kernel_launch(void* const* d_in, const int* in_sizes, int n_in,
                              void* d_out, int out_size, void* d_ws, size_t ws_size,
                              hipStream_t stream) {
  const float* S = (const float*)d_in[0];
  const float* Qm = (const float*)d_in[1];
  const float* Wb = (const float*)d_in[2];
  const float* gamma = (const float*)d_in[3];
  float* out = (float*)d_out;
  char* base = (char*)d_ws;
  // persistent region
  float* FX   = (float*)(base);                 // 240*640*4 = 614,400
  short* Kh   = (short*)(base + 614400);        // 512,000
  short* Kl   = (short*)(base + 1126400);       // 512,000
  float* WK   = (float*)(base + 1638400);       // 40,960
  float* Xb   = (float*)(base + 1679360);       // 25,600
  float* Acc  = (float*)(base + 1704960);       // 640*640*4 = 1,638,400
  // Wt region: live only until gemm_feat_sk; A-splits alias it after
  char* wt = base + 3343360;
  short* Wth = (short*)(wt);                    // 640*3072*2 = 3,932,160
  short* Wtl = (short*)(wt + 3932160);          // 3,932,160 -> end 11,207,680
  short* Aph = (short*)(wt);                    // 416*416*2 = 346,112 (alias)
  short* Apl = (short*)(wt + 346112);           // 346,112

  hipMemsetAsync(Acc, 0, 640 * DF * sizeof(float), stream);
  split_wt<<<dim3(10, 48), 256, 0, stream>>>(Wb, Wth, Wtl);
  gemm_feat_sk<<<dim3(10, 10, KSPLIT), 256, 0, stream>>>(S, Qm, Wth, Wtl, Acc);
  finalize_feat<<<1600, 256, 0, stream>>>(Acc, Kh, Kl, FX);
  gemm_aul<<<dim3(7, 7), 256, 0, stream>>>(Kh, Kl, Aph, Apl);
  solve_rep<<<1, 512, 0, stream>>>(Aph, Apl, Xb);
  wk_kernel<<<40, 256, 0, stream>>>(Xb, Kh, Kl, WK);
  logits_kernel<<<15, 256, 0, stream>>>(FX, WK, gamma, out);
}

// Round 7
// 361.590 us; speedup vs baseline: 1.4043x; 1.4043x over previous
//
#include <hip/hip_runtime.h>
#include <math.h>

#define DIN 3072
#define DF 640
#define MROWS 400
#define QROWS 240
#define NMAT 400
#define PN 416          // padded A dim (13*32, 26*16)
#define NRHS 16
#define CREG 50.0f
#define PVSTEPS 6
#define CSTEPS 27       // Chebyshev: kappa~62 -> q~0.776 -> rel ~2e-3
#define KSPLIT 8        // gemm_feat split-K factor
#define GBLK 13         // solve blocks; each owns 32 rows of A in LDS
#define CROWS 32

typedef __attribute__((ext_vector_type(8))) short bf8v;   // 8 bf16 (4 VGPRs)
typedef __attribute__((ext_vector_type(4))) float f32x4;  // MFMA acc

__device__ __forceinline__ short bf16_rn(float x) {
  unsigned u = __float_as_uint(x);
  u += 0x7FFFu + ((u >> 16) & 1u);
  return (short)(u >> 16);
}
__device__ __forceinline__ void split_sh(float x, short& h, short& l) {
  h = bf16_rn(x);
  float hf = __uint_as_float(((unsigned)(unsigned short)h) << 16);
  l = bf16_rn(x - hf);
}
__device__ __forceinline__ float bf2f(short h) {
  return __uint_as_float(((unsigned)(unsigned short)h) << 16);
}

// ---- transpose + split Wb(3072x640) -> Wth,Wtl [640][3072] bf16 -----------
__global__ __launch_bounds__(256) void split_wt(const float* __restrict__ Wb,
                                                short* __restrict__ H,
                                                short* __restrict__ L) {
  __shared__ float T[64][65];
  int n0 = blockIdx.x * 64;   // over DF
  int k0 = blockIdx.y * 64;   // over DIN
  int c = threadIdx.x & 63, r0 = threadIdx.x >> 6;
#pragma unroll
  for (int i = 0; i < 16; ++i) {
    int r = i * 4 + r0;
    T[r][c] = Wb[(size_t)(k0 + r) * DF + n0 + c];
  }
  __syncthreads();
#pragma unroll
  for (int i = 0; i < 16; ++i) {
    int n = i * 4 + r0;
    float x = T[c][n];              // Wb[k0+c][n0+n]
    short h, l; split_sh(x, h, l);
    size_t o = (size_t)(n0 + n) * DIN + k0 + c;
    H[o] = h; L[o] = l;
  }
}

// ---- split-K MFMA GEMM: partial [S;Q] @ Wb -> atomicAdd into Acc(640x640) -
__global__ __launch_bounds__(256) void gemm_feat_sk(const float* __restrict__ S,
                                                    const float* __restrict__ Qm,
                                                    const short* __restrict__ Bh,
                                                    const short* __restrict__ Bl,
                                                    float* __restrict__ Acc) {
  __shared__ float As[64][68];
  __shared__ short Bsh[64][72];
  __shared__ short Bsl[64][72];
  int tid = threadIdx.x;
  int wave = tid >> 6, lane = tid & 63, l16 = lane & 15, quad = lane >> 4;
  int by = blockIdx.y, bx = blockIdx.x, bz = blockIdx.z;
  int colBase = bx * 64;
  int kbeg = bz * (DIN / KSPLIT), kend = kbeg + (DIN / KSPLIT);
  f32x4 acc[4] = {{0,0,0,0},{0,0,0,0},{0,0,0,0},{0,0,0,0}};
  for (int k0 = kbeg; k0 < kend; k0 += 64) {
    __syncthreads();
#pragma unroll
    for (int p = 0; p < 4; ++p) {
      int cid = tid + 256 * p;            // 0..1023
      int row = cid >> 4, kc = cid & 15;
      int arow = by * 64 + row;
      const float* sr = (arow < MROWS) ? (S + (size_t)arow * DIN)
                                       : (Qm + (size_t)(arow - MROWS) * DIN);
      float4 v = *reinterpret_cast<const float4*>(sr + k0 + kc * 4);
      *reinterpret_cast<float4*>(&As[row][kc * 4]) = v;
    }
#pragma unroll
    for (int p = 0; p < 2; ++p) {
      int cid = tid + 256 * p;            // 0..511
      int nn = cid >> 3, kc = cid & 7;
      size_t src = (size_t)(colBase + nn) * DIN + k0 + kc * 8;
      *reinterpret_cast<bf8v*>(&Bsh[nn][kc * 8]) = *reinterpret_cast<const bf8v*>(Bh + src);
      *reinterpret_cast<bf8v*>(&Bsl[nn][kc * 8]) = *reinterpret_cast<const bf8v*>(Bl + src);
    }
    __syncthreads();
#pragma unroll
    for (int kk = 0; kk < 64; kk += 32) {
      int ko = kk + quad * 8;
      float4 a0 = *reinterpret_cast<const float4*>(&As[wave * 16 + l16][ko]);
      float4 a1 = *reinterpret_cast<const float4*>(&As[wave * 16 + l16][ko + 4]);
      float av[8] = {a0.x, a0.y, a0.z, a0.w, a1.x, a1.y, a1.z, a1.w};
      bf8v ah, al;
#pragma unroll
      for (int j = 0; j < 8; ++j) { short h, l; split_sh(av[j], h, l); ah[j] = h; al[j] = l; }
#pragma unroll
      for (int t = 0; t < 4; ++t) {
        bf8v bh = *reinterpret_cast<const bf8v*>(&Bsh[t * 16 + l16][ko]);
        bf8v bl = *reinterpret_cast<const bf8v*>(&Bsl[t * 16 + l16][ko]);
        acc[t] = __builtin_amdgcn_mfma_f32_16x16x32_bf16(ah, bh, acc[t], 0, 0, 0);
        acc[t] = __builtin_amdgcn_mfma_f32_16x16x32_bf16(ah, bl, acc[t], 0, 0, 0);
        acc[t] = __builtin_amdgcn_mfma_f32_16x16x32_bf16(al, bh, acc[t], 0, 0, 0);
      }
    }
  }
  int row0 = by * 64 + wave * 16;
#pragma unroll
  for (int t = 0; t < 4; ++t) {
#pragma unroll
    for (int r = 0; r < 4; ++r) {
      int row = row0 + quad * 4 + r;
      int col = colBase + t * 16 + l16;
      atomicAdd(&Acc[(size_t)row * DF + col], acc[t][r]);
    }
  }
}

// ---- finalize: Acc -> Kh,Kl (rows<400) / FX (rows>=400) -------------------
__global__ __launch_bounds__(256) void finalize_feat(const float* __restrict__ Acc,
                                                     short* __restrict__ Kh,
                                                     short* __restrict__ Kl,
                                                     float* __restrict__ FX) {
  int idx = blockIdx.x * 256 + threadIdx.x;   // < 640*640
  if (idx >= 640 * DF) return;
  float v = Acc[idx];
  int row = idx / DF, col = idx - row * DF;
  if (row < MROWS) {
    short h, l; split_sh(v, h, l);
    Kh[(size_t)row * DF + col] = h;
    Kl[(size_t)row * DF + col] = l;
  } else {
    FX[(size_t)(row - MROWS) * DF + col] = v;
  }
}

// ---- MFMA: A(416x416) = K K^T + 50 I (zero-padded), bf16 hi/lo out --------
__global__ __launch_bounds__(256) void gemm_aul(const short* __restrict__ Kh,
                                                const short* __restrict__ Kl,
                                                short* __restrict__ Aph,
                                                short* __restrict__ Apl) {
  int tid = threadIdx.x;
  int wave = tid >> 6, lane = tid & 63;
  int l16 = lane & 15, quad = lane >> 4;
  int row0 = blockIdx.y * 64 + wave * 16;
  int colBase = blockIdx.x * 64;
  bool aValid = (row0 < MROWS);
  const bf8v bzero = {0,0,0,0,0,0,0,0};
  f32x4 acc[4] = {{0,0,0,0},{0,0,0,0},{0,0,0,0},{0,0,0,0}};
  for (int k0 = 0; k0 < DF; k0 += 32) {
    int ka = k0 + quad * 8;
    bf8v ah = bzero, al = bzero;
    if (aValid) {
      size_t ao = (size_t)(row0 + l16) * DF + ka;
      ah = *reinterpret_cast<const bf8v*>(Kh + ao);
      al = *reinterpret_cast<const bf8v*>(Kl + ao);
    }
#pragma unroll
    for (int t = 0; t < 4; ++t) {
      int colt = colBase + t * 16;
      bf8v bh = bzero, bl = bzero;
      if (colt < MROWS) {
        size_t bo = (size_t)(colt + l16) * DF + ka;
        bh = *reinterpret_cast<const bf8v*>(Kh + bo);
        bl = *reinterpret_cast<const bf8v*>(Kl + bo);
      }
      acc[t] = __builtin_amdgcn_mfma_f32_16x16x32_bf16(ah, bh, acc[t], 0, 0, 0);
      acc[t] = __builtin_amdgcn_mfma_f32_16x16x32_bf16(ah, bl, acc[t], 0, 0, 0);
      acc[t] = __builtin_amdgcn_mfma_f32_16x16x32_bf16(al, bh, acc[t], 0, 0, 0);
    }
  }
  if (row0 >= PN) return;
#pragma unroll
  for (int t = 0; t < 4; ++t) {
    int colt = colBase + t * 16;
    if (colt >= PN) continue;
#pragma unroll
    for (int r = 0; r < 4; ++r) {
      int row = row0 + quad * 4 + r;
      int col = colt + l16;
      float v = acc[t][r];
      if (row == col && row < MROWS) v += CREG;
      short h, l; split_sh(v, h, l);
      size_t o = (size_t)row * PN + col;
      Aph[o] = h; Apl[o] = l;
    }
  }
}

// ---- distributed solve: 13 blocks, each owns 32 rows of A in LDS ----------
// LDS is immune to the grid-barrier fences' L2 invalidation (R5 lesson);
// per step only the 26.6KB d-iterate crosses blocks. PV for lambda_max,
// then Chebyshev on A X = P. Matvec slice via MFMA from LDS fragments.
__global__ __launch_bounds__(256) void solve_dist(const short* __restrict__ Aph,
                                                  const short* __restrict__ Apl,
                                                  short* __restrict__ Dh,
                                                  short* __restrict__ Dl,
                                                  short* __restrict__ Vg,
                                                  unsigned* __restrict__ bar,
                                                  float* __restrict__ X) {
  __shared__ short Ah[CROWS][PN + 8];    // 27.1 KB
  __shared__ short Al[CROWS][PN + 8];    // 27.1 KB
  __shared__ short dh[16][PN + 8];       // 13.6 KB  [c][j]
  __shared__ short dl[16][PN + 8];       // 13.6 KB
  __shared__ float part[4][16][17];      // per-wave matvec partials, 4.4 KB
  __shared__ float scal[2];
  int tid = threadIdx.x, b = blockIdx.x;
  int r0 = b * CROWS;
  int wave = tid >> 6, lane = tid & 63, l16 = lane & 15, quad = lane >> 4;
  int mt = wave & 1, kh = wave >> 1;           // m-tile, k-half per wave
  int kcb = kh ? 7 : 0, kce = kh ? 13 : 7;

  // stage A chunk (rows r0..r0+31) into LDS
  for (int e = tid; e < CROWS * (PN / 8); e += 256) {
    int rr = e / (PN / 8), jc = (e - (e / (PN / 8)) * (PN / 8)) * 8;
    size_t src = (size_t)(r0 + rr) * PN + jc;
    *reinterpret_cast<bf8v*>(&Ah[rr][jc]) = *reinterpret_cast<const bf8v*>(Aph + src);
    *reinterpret_cast<bf8v*>(&Al[rr][jc]) = *reinterpret_cast<const bf8v*>(Apl + src);
  }
  // zero d buffers
  for (int e = tid; e < 16 * (PN + 8); e += 256) {
    (&dh[0][0])[e] = 0; (&dl[0][0])[e] = 0;
  }
  __syncthreads();
  // PV start vector in dh[0]
  for (int e = tid; e < PN; e += 256)
    dh[0][e] = bf16_rn((e < NMAT) ? (1.f + 0.125f * (float)(e & 7)) : 0.f);
  __syncthreads();

  unsigned ph = 0;
  auto gridbar = [&]() {
    __syncthreads();
    ++ph;
    if (tid == 0) {
      __threadfence();
      atomicAdd(bar, 1u);
      unsigned tgt = ph * GBLK;
      while (atomicAdd(bar, 0u) < tgt) __builtin_amdgcn_s_sleep(4);
      __threadfence();
    }
    __syncthreads();
  };

  // ---- power iteration (6 steps, hi-only matvec on column 0) ----
  for (int s = 0; s < PVSTEPS; ++s) {
    f32x4 acc = {0, 0, 0, 0};
    for (int kc = kcb; kc < kce; ++kc) {
      int jb = 32 * kc + quad * 8;
      bf8v bh = *reinterpret_cast<const bf8v*>(&dh[l16][jb]);
      bf8v ah = *reinterpret_cast<const bf8v*>(&Ah[mt * 16 + l16][jb]);
      acc = __builtin_amdgcn_mfma_f32_16x16x32_bf16(ah, bh, acc, 0, 0, 0);
    }
#pragma unroll
    for (int r = 0; r < 4; ++r) part[wave][quad * 4 + r][l16] = acc[r];
    __syncthreads();
    if (tid < CROWS) {
      int m2 = tid >> 4, rl = tid & 15;
      float y = (part[m2][rl][0] + part[m2 + 2][rl][0]) * (1.f / 4096.f);
      Vg[r0 + tid] = bf16_rn(y);
    }
    gridbar();
    for (int e = tid; e < PN; e += 256) {
      dh[1][e] = dh[0][e];          // prev
      dh[0][e] = Vg[e];             // cur (bf16 bits)
    }
    __syncthreads();
  }
  // ---- Rayleigh quotient -> interval (redundant per block, deterministic) --
  if (tid == 0) {
    float n = 0.f, dd = 0.f;
    for (int j = 0; j < NMAT; ++j) {
      float vp = bf2f(dh[1][j]), vc = bf2f(dh[0][j]);
      n += vp * vc; dd += vp * vp;
    }
    float rqv = 4096.f * n / dd;
    float bb = 1.25f * rqv;
    if (!(bb > 800.f)) bb = 12000.f;   // degenerate/NaN fallback
    if (bb > 100000.f) bb = 100000.f;
    scal[0] = 0.5f * (bb + CREG);      // theta
    scal[1] = 0.5f * (bb - CREG);      // delta
  }
  __syncthreads();
  float theta = scal[0], delta = scal[1];
  float sigma = theta / delta, rho = 1.f / sigma;

  // ---- Chebyshev init (all analytic, no exchange needed) ----
  for (int e = tid; e < 16 * (PN + 8); e += 256) {
    (&dh[0][0])[e] = 0; (&dl[0][0])[e] = 0;
  }
  __syncthreads();
  for (int e = tid; e < NMAT * 16; e += 256) {
    int j = e >> 4, c = e & 15;
    if ((j / 25) == c) {
      float dv = 1.f / theta;
      short h, l; split_sh(dv, h, l);
      dh[c][j] = h; dl[c][j] = l;
    }
  }
  float xr[2], rr2[2], dr[2];
#pragma unroll
  for (int m = 0; m < 2; ++m) {
    int gi = r0 + (tid >> 4) + 16 * m, c = tid & 15;
    float pc = (gi < NMAT && (gi / 25) == c) ? 1.f : 0.f;
    xr[m] = 0.f; rr2[m] = pc; dr[m] = pc / theta;
  }
  __syncthreads();

  // ---- Chebyshev steps (last d needs no matvec: CSTEPS-1 full + final add)
  for (int k = 0; k < CSTEPS - 1; ++k) {
    f32x4 acc = {0, 0, 0, 0};
    for (int kc = kcb; kc < kce; ++kc) {
      int jb = 32 * kc + quad * 8;
      bf8v bh = *reinterpret_cast<const bf8v*>(&dh[l16][jb]);
      bf8v bl = *reinterpret_cast<const bf8v*>(&dl[l16][jb]);
      bf8v ah = *reinterpret_cast<const bf8v*>(&Ah[mt * 16 + l16][jb]);
      bf8v al = *reinterpret_cast<const bf8v*>(&Al[mt * 16 + l16][jb]);
      acc = __builtin_amdgcn_mfma_f32_16x16x32_bf16(ah, bh, acc, 0, 0, 0);
      acc = __builtin_amdgcn_mfma_f32_16x16x32_bf16(ah, bl, acc, 0, 0, 0);
      acc = __builtin_amdgcn_mfma_f32_16x16x32_bf16(al, bh, acc, 0, 0, 0);
    }
#pragma unroll
    for (int r = 0; r < 4; ++r) part[wave][quad * 4 + r][l16] = acc[r];
    __syncthreads();
    float rho1 = 1.f / (2.f * sigma - rho);
    float s1 = rho1 * rho, s2 = 2.f * rho1 / delta;
    rho = rho1;
#pragma unroll
    for (int m = 0; m < 2; ++m) {
      int rl = (tid >> 4) + 16 * m, c = tid & 15;
      int m2 = rl >> 4, rli = rl & 15;
      float mv = part[m2][rli][c] + part[m2 + 2][rli][c];
      xr[m] += dr[m];
      rr2[m] -= mv;
      float dn = s1 * dr[m] + s2 * rr2[m];
      dr[m] = dn;
      short h, l; split_sh(dn, h, l);
      int gi = r0 + rl;
      Dh[c * PN + gi] = h;
      Dl[c * PN + gi] = l;
    }
    gridbar();
    for (int e = tid; e < 16 * PN; e += 256) {
      int c = e / PN, j = e - c * PN;
      dh[c][j] = Dh[e];
      dl[c][j] = Dl[e];
    }
    __syncthreads();
  }
#pragma unroll
  for (int m = 0; m < 2; ++m) {
    int gi = r0 + (tid >> 4) + 16 * m, c = tid & 15;
    float xf = xr[m] + dr[m];
    if (gi < NMAT) X[gi * NRHS + c] = xf;
  }
}

// ---- WK[j][d] = sum_i X[i][j] K[i][d], K = Kh+Kl --------------------------
__global__ __launch_bounds__(256) void wk_kernel(const float* __restrict__ X,
                                                 const short* __restrict__ Kh,
                                                 const short* __restrict__ Kl,
                                                 float* __restrict__ WK) {
  int idx = blockIdx.x * 256 + threadIdx.x;   // < 16*640
  int j = idx / DF;
  int d = idx - j * DF;
  float acc = 0.f;
  for (int i = 0; i < NMAT; ++i) {
    float kv = bf2f(Kh[(size_t)i * DF + d]) + bf2f(Kl[(size_t)i * DF + d]);
    acc += X[i * NRHS + j] * kv;
  }
  WK[idx] = acc;
}

// ---- logits[q][c] = -gamma * dot(FX[q], WK[c]) ----------------------------
__global__ __launch_bounds__(256) void logits_kernel(const float* __restrict__ FX,
                                                     const float* __restrict__ WK,
                                                     const float* __restrict__ gamma,
                                                     float* __restrict__ out) {
  int idx = blockIdx.x * 256 + threadIdx.x;
  int q = idx >> 4, c = idx & 15;
  const float* fr = FX + (size_t)q * DF;
  const float* wr = WK + (size_t)c * DF;
  float acc = 0.f;
  for (int d = 0; d < DF; ++d) acc += fr[d] * wr[d];
  out[idx] = -gamma[0] * acc;
}

extern "C" void kernel_launch(void* const* d_in, const int* in_sizes, int n_in,
                              void* d_out, int out_size, void* d_ws, size_t ws_size,
                              hipStream_t stream) {
  const float* S = (const float*)d_in[0];
  const float* Qm = (const float*)d_in[1];
  const float* Wb = (const float*)d_in[2];
  const float* gamma = (const float*)d_in[3];
  float* out = (float*)d_out;
  char* base = (char*)d_ws;
  // persistent region
  float* FX   = (float*)(base);                 // 240*640*4 = 614,400
  short* Kh   = (short*)(base + 614400);        // 512,000
  short* Kl   = (short*)(base + 1126400);       // 512,000
  float* WK   = (float*)(base + 1638400);       // 40,960
  float* Xb   = (float*)(base + 1679360);       // 25,600
  short* Dh   = (short*)(base + 1704960);       // 16*416*2 = 13,312
  short* Dl   = (short*)(base + 1718272);       // 13,312
  short* Vg   = (short*)(base + 1731584);       // 416*2 -> 832
  unsigned* bar = (unsigned*)(base + 1732416);  // 64
  float* Acc  = (float*)(base + 1732480);       // 640*640*4 = 1,638,400
  // Wt region: live only until gemm_feat_sk; A-splits alias it after
  char* wt = base + 3370880;
  short* Wth = (short*)(wt);                    // 640*3072*2 = 3,932,160
  short* Wtl = (short*)(wt + 3932160);          // -> end 11,235,200
  short* Aph = (short*)(wt);                    // 416*416*2 = 346,112 (alias)
  short* Apl = (short*)(wt + 346112);           // 346,112

  // zero bar + Acc (adjacent) in one memset
  hipMemsetAsync((void*)bar, 0, 64 + 640 * DF * sizeof(float), stream);
  split_wt<<<dim3(10, 48), 256, 0, stream>>>(Wb, Wth, Wtl);
  gemm_feat_sk<<<dim3(10, 10, KSPLIT), 256, 0, stream>>>(S, Qm, Wth, Wtl, Acc);
  finalize_feat<<<1600, 256, 0, stream>>>(Acc, Kh, Kl, FX);
  gemm_aul<<<dim3(7, 7), 256, 0, stream>>>(Kh, Kl, Aph, Apl);
  solve_dist<<<GBLK, 256, 0, stream>>>(Aph, Apl, Dh, Dl, Vg, bar, Xb);
  wk_kernel<<<40, 256, 0, stream>>>(Xb, Kh, Kl, WK);
  logits_kernel<<<15, 256, 0, stream>>>(FX, WK, gamma, out);
}

// Round 8
// 287.226 us; speedup vs baseline: 1.7679x; 1.2589x over previous
//
#include <hip/hip_runtime.h>
#include <math.h>

#define DIN 3072
#define DF 640
#define MROWS 400
#define QROWS 240
#define NMAT 400
#define PN 416          // padded A dim (13*32, 26*16)
#define NRHS 16
#define CREG 50.0f
#define PVSTEPS 6
#define CSTEPS 27       // Chebyshev: kappa~62 -> q~0.776 -> rel ~2e-3
#define KSPLIT 8        // gemm_feat split-K factor
#define GBLK 13         // solve blocks; each owns 32 cols of A in LDS
#define CROWS 32

typedef __attribute__((ext_vector_type(8))) short bf8v;   // 8 bf16 (4 VGPRs)
typedef __attribute__((ext_vector_type(4))) float f32x4;  // MFMA acc

__device__ __forceinline__ short bf16_rn(float x) {
  unsigned u = __float_as_uint(x);
  u += 0x7FFFu + ((u >> 16) & 1u);
  return (short)(u >> 16);
}
__device__ __forceinline__ void split_sh(float x, short& h, short& l) {
  h = bf16_rn(x);
  float hf = __uint_as_float(((unsigned)(unsigned short)h) << 16);
  l = bf16_rn(x - hf);
}
__device__ __forceinline__ float bf2f(short h) {
  return __uint_as_float(((unsigned)(unsigned short)h) << 16);
}

// ---- split-K MFMA GEMM with fused B transpose+split (no split_wt kernel) --
// partial [S;Q](640x3072) @ Wb(3072x640) -> atomicAdd into Acc(640x640)
__global__ __launch_bounds__(256) void gemm_feat_sk(const float* __restrict__ S,
                                                    const float* __restrict__ Qm,
                                                    const float* __restrict__ Wb,
                                                    float* __restrict__ Acc) {
  __shared__ float As[64][68];
  __shared__ short Bsh[64][72];
  __shared__ short Bsl[64][72];
  int tid = threadIdx.x;
  int wave = tid >> 6, lane = tid & 63, l16 = lane & 15, quad = lane >> 4;
  int by = blockIdx.y, bx = blockIdx.x, bz = blockIdx.z;
  int colBase = bx * 64;
  int kbeg = bz * (DIN / KSPLIT), kend = kbeg + (DIN / KSPLIT);
  f32x4 acc[4] = {{0,0,0,0},{0,0,0,0},{0,0,0,0},{0,0,0,0}};
  for (int k0 = kbeg; k0 < kend; k0 += 64) {
    __syncthreads();
    // stage A tile: 64 rows x 64 floats, coalesced float4
#pragma unroll
    for (int p = 0; p < 4; ++p) {
      int cid = tid + 256 * p;            // 0..1023
      int row = cid >> 4, kc = cid & 15;
      int arow = by * 64 + row;
      const float* sr = (arow < MROWS) ? (S + (size_t)arow * DIN)
                                       : (Qm + (size_t)(arow - MROWS) * DIN);
      float4 v = *reinterpret_cast<const float4*>(sr + k0 + kc * 4);
      *reinterpret_cast<float4*>(&As[row][kc * 4]) = v;
    }
    // stage B tile: fp32 [64k x 64n] -> transpose + split into Bsh/Bsl[n][k]
#pragma unroll
    for (int p = 0; p < 4; ++p) {
      int cid = tid + 256 * p;            // 0..1023
      int r = cid >> 4, c4 = (cid & 15) * 4;
      float4 w = *reinterpret_cast<const float4*>(Wb + (size_t)(k0 + r) * DF + colBase + c4);
      short h, l;
      split_sh(w.x, h, l); Bsh[c4 + 0][r] = h; Bsl[c4 + 0][r] = l;
      split_sh(w.y, h, l); Bsh[c4 + 1][r] = h; Bsl[c4 + 1][r] = l;
      split_sh(w.z, h, l); Bsh[c4 + 2][r] = h; Bsl[c4 + 2][r] = l;
      split_sh(w.w, h, l); Bsh[c4 + 3][r] = h; Bsl[c4 + 3][r] = l;
    }
    __syncthreads();
#pragma unroll
    for (int kk = 0; kk < 64; kk += 32) {
      int ko = kk + quad * 8;
      float4 a0 = *reinterpret_cast<const float4*>(&As[wave * 16 + l16][ko]);
      float4 a1 = *reinterpret_cast<const float4*>(&As[wave * 16 + l16][ko + 4]);
      float av[8] = {a0.x, a0.y, a0.z, a0.w, a1.x, a1.y, a1.z, a1.w};
      bf8v ah, al;
#pragma unroll
      for (int j = 0; j < 8; ++j) { short h, l; split_sh(av[j], h, l); ah[j] = h; al[j] = l; }
#pragma unroll
      for (int t = 0; t < 4; ++t) {
        bf8v bh = *reinterpret_cast<const bf8v*>(&Bsh[t * 16 + l16][ko]);
        bf8v bl = *reinterpret_cast<const bf8v*>(&Bsl[t * 16 + l16][ko]);
        acc[t] = __builtin_amdgcn_mfma_f32_16x16x32_bf16(ah, bh, acc[t], 0, 0, 0);
        acc[t] = __builtin_amdgcn_mfma_f32_16x16x32_bf16(ah, bl, acc[t], 0, 0, 0);
        acc[t] = __builtin_amdgcn_mfma_f32_16x16x32_bf16(al, bh, acc[t], 0, 0, 0);
      }
    }
  }
  int row0 = by * 64 + wave * 16;
#pragma unroll
  for (int t = 0; t < 4; ++t) {
#pragma unroll
    for (int r = 0; r < 4; ++r) {
      int row = row0 + quad * 4 + r;
      int col = colBase + t * 16 + l16;
      atomicAdd(&Acc[(size_t)row * DF + col], acc[t][r]);
    }
  }
}

// ---- finalize: Acc -> Kh,Kl (rows<400) / FX (rows>=400) -------------------
__global__ __launch_bounds__(256) void finalize_feat(const float* __restrict__ Acc,
                                                     short* __restrict__ Kh,
                                                     short* __restrict__ Kl,
                                                     float* __restrict__ FX) {
  int idx = blockIdx.x * 256 + threadIdx.x;   // < 640*640
  if (idx >= 640 * DF) return;
  float v = Acc[idx];
  int row = idx / DF, col = idx - row * DF;
  if (row < MROWS) {
    short h, l; split_sh(v, h, l);
    Kh[(size_t)row * DF + col] = h;
    Kl[(size_t)row * DF + col] = l;
  } else {
    FX[(size_t)(row - MROWS) * DF + col] = v;
  }
}

// ---- MFMA: A(416x416) = K K^T + 50 I (zero-padded), bf16 hi/lo out --------
__global__ __launch_bounds__(256) void gemm_aul(const short* __restrict__ Kh,
                                                const short* __restrict__ Kl,
                                                short* __restrict__ Aph,
                                                short* __restrict__ Apl) {
  int tid = threadIdx.x;
  int wave = tid >> 6, lane = tid & 63;
  int l16 = lane & 15, quad = lane >> 4;
  int row0 = blockIdx.y * 64 + wave * 16;
  int colBase = blockIdx.x * 64;
  bool aValid = (row0 < MROWS);
  const bf8v bzero = {0,0,0,0,0,0,0,0};
  f32x4 acc[4] = {{0,0,0,0},{0,0,0,0},{0,0,0,0},{0,0,0,0}};
  for (int k0 = 0; k0 < DF; k0 += 32) {
    int ka = k0 + quad * 8;
    bf8v ah = bzero, al = bzero;
    if (aValid) {
      size_t ao = (size_t)(row0 + l16) * DF + ka;
      ah = *reinterpret_cast<const bf8v*>(Kh + ao);
      al = *reinterpret_cast<const bf8v*>(Kl + ao);
    }
#pragma unroll
    for (int t = 0; t < 4; ++t) {
      int colt = colBase + t * 16;
      bf8v bh = bzero, bl = bzero;
      if (colt < MROWS) {
        size_t bo = (size_t)(colt + l16) * DF + ka;
        bh = *reinterpret_cast<const bf8v*>(Kh + bo);
        bl = *reinterpret_cast<const bf8v*>(Kl + bo);
      }
      acc[t] = __builtin_amdgcn_mfma_f32_16x16x32_bf16(ah, bh, acc[t], 0, 0, 0);
      acc[t] = __builtin_amdgcn_mfma_f32_16x16x32_bf16(ah, bl, acc[t], 0, 0, 0);
      acc[t] = __builtin_amdgcn_mfma_f32_16x16x32_bf16(al, bh, acc[t], 0, 0, 0);
    }
  }
  if (row0 >= PN) return;
#pragma unroll
  for (int t = 0; t < 4; ++t) {
    int colt = colBase + t * 16;
    if (colt >= PN) continue;
#pragma unroll
    for (int r = 0; r < 4; ++r) {
      int row = row0 + quad * 4 + r;
      int col = colt + l16;
      float v = acc[t][r];
      if (row == col && row < MROWS) v += CREG;
      short h, l; split_sh(v, h, l);
      size_t o = (size_t)row * PN + col;
      Aph[o] = h; Apl[o] = l;
    }
  }
}

// ---- column-split distributed solve: 13 blocks, each owns 32 cols of A ----
// Partial matvec from purely LOCAL data (A cols + own d rows); fp32 partials
// exchanged via device-scope atomicAdd into double-buffered Y (L3-coherent,
// NO threadfence/L2-invalidate). Barrier: release fetch_add + relaxed poll.
// Read-back of own 2KB slice via atomicExch (coherent read + re-zero in one).
__global__ __launch_bounds__(256) void solve_dist(const short* __restrict__ Aph,
                                                  const short* __restrict__ Apl,
                                                  float* __restrict__ Y0,
                                                  float* __restrict__ Y1,
                                                  float* __restrict__ V0,
                                                  float* __restrict__ V1,
                                                  float* __restrict__ rq,
                                                  unsigned* __restrict__ bar,
                                                  float* __restrict__ X) {
  __shared__ short AsT_h[PN][40];   // AsT[i][jl] = A[r0+jl][i] (sym) 33.3KB
  __shared__ short AsT_l[PN][40];   // 33.3KB
  __shared__ short dbT_h[16][40];   // d B-operand [c][k_local]
  __shared__ short dbT_l[16][40];
  __shared__ float pvp[CROWS], pvc[CROWS];
  __shared__ float scal[2];
  int tid = threadIdx.x, b = blockIdx.x;
  int r0 = b * CROWS;
  int wave = tid >> 6, lane = tid & 63, l16 = lane & 15, quad = lane >> 4;

  // stage A^T slice: read rows r0..r0+31 (contiguous), write transposed
  for (int e = tid; e < CROWS * (PN / 8); e += 256) {
    int jl = e / (PN / 8), ic = e - (e / (PN / 8)) * (PN / 8);
    bf8v vh = *reinterpret_cast<const bf8v*>(Aph + (size_t)(r0 + jl) * PN + ic * 8);
    bf8v vl = *reinterpret_cast<const bf8v*>(Apl + (size_t)(r0 + jl) * PN + ic * 8);
#pragma unroll
    for (int u = 0; u < 8; ++u) {
      AsT_h[ic * 8 + u][jl] = vh[u];
      AsT_l[ic * 8 + u][jl] = vl[u];
    }
  }
  for (int e = tid; e < 16 * 40; e += 256) {
    (&dbT_h[0][0])[e] = 0; (&dbT_l[0][0])[e] = 0;
  }
  __syncthreads();
  if (tid < CROWS) {
    int gi = r0 + tid;
    float v = (gi < NMAT) ? (1.f + 0.125f * (float)(gi & 7)) : 0.f;
    pvc[tid] = v;
    dbT_h[0][tid] = bf16_rn(v);
  }
  __syncthreads();

  unsigned ph = 0;
  auto gridbar = [&]() {
    __syncthreads();
    ++ph;
    if (tid == 0) {
      unsigned tgt = ph * GBLK;
      __hip_atomic_fetch_add(bar, 1u, __ATOMIC_RELEASE, __HIP_MEMORY_SCOPE_AGENT);
      while (__hip_atomic_load(bar, __ATOMIC_RELAXED, __HIP_MEMORY_SCOPE_AGENT) < tgt)
        __builtin_amdgcn_s_sleep(2);
    }
    __syncthreads();
  };

  // ---- power iteration: partial y = A[:,own] @ v_own, hi only, col 0 ----
  for (int s = 0; s < PVSTEPS; ++s) {
    float* Yv = (s & 1) ? V1 : V0;
    for (int t = wave; t < 26; t += 4) {
      f32x4 acc = {0, 0, 0, 0};
      bf8v bh = *reinterpret_cast<const bf8v*>(&dbT_h[l16][quad * 8]);
      bf8v ah = *reinterpret_cast<const bf8v*>(&AsT_h[t * 16 + l16][quad * 8]);
      acc = __builtin_amdgcn_mfma_f32_16x16x32_bf16(ah, bh, acc, 0, 0, 0);
      if (l16 == 0) {
#pragma unroll
        for (int r_ = 0; r_ < 4; ++r_)
          atomicAdd(&Yv[t * 16 + quad * 4 + r_], acc[r_]);
      }
    }
    gridbar();
    if (tid < CROWS) {
      float y = atomicExch(&Yv[r0 + tid], 0.f);   // coherent read + re-zero
      float v = y * (1.f / 4096.f);
      pvp[tid] = pvc[tid];
      pvc[tid] = v;
      dbT_h[0][tid] = bf16_rn(v);
    }
    __syncthreads();
  }
  // ---- Rayleigh quotient (partial dots over own slice) ----
  if (tid == 0) {
    float n = 0.f, dd = 0.f;
    for (int u = 0; u < CROWS; ++u) { n += pvp[u] * pvc[u]; dd += pvp[u] * pvp[u]; }
    atomicAdd(&rq[0], n);
    atomicAdd(&rq[1], dd);
  }
  gridbar();
  if (tid == 0) {
    float rn = atomicAdd(&rq[0], 0.f), rd = atomicAdd(&rq[1], 0.f);
    float rqv = 4096.f * rn / rd;
    float bb = 1.25f * rqv;
    if (!(bb > 800.f)) bb = 12000.f;   // degenerate/NaN fallback
    if (bb > 100000.f) bb = 100000.f;
    scal[0] = 0.5f * (bb + CREG);      // theta
    scal[1] = 0.5f * (bb - CREG);      // delta
  }
  __syncthreads();
  float theta = scal[0], delta = scal[1];
  float sigma = theta / delta, rho = 1.f / sigma;

  // ---- Chebyshev init: thread owns (rl = tid>>4 + 16m, c = tid&15) ----
  float xr[2], rr[2], dr[2];
#pragma unroll
  for (int m = 0; m < 2; ++m) {
    int rl = (tid >> 4) + 16 * m, c = tid & 15, gi = r0 + rl;
    float pc = (gi < NMAT && (gi / 25) == c) ? 1.f : 0.f;
    xr[m] = 0.f; rr[m] = pc; dr[m] = pc / theta;
    short h, l; split_sh(dr[m], h, l);
    dbT_h[c][rl] = h; dbT_l[c][rl] = l;
  }
  __syncthreads();

  // ---- Chebyshev steps (Saad Alg 12.1); CSTEPS-1 matvecs + final add ----
  for (int k = 0; k < CSTEPS - 1; ++k) {
    float* Yv = (k & 1) ? Y1 : Y0;
    for (int t = wave; t < 26; t += 4) {
      f32x4 acc = {0, 0, 0, 0};
      bf8v bh = *reinterpret_cast<const bf8v*>(&dbT_h[l16][quad * 8]);
      bf8v bl = *reinterpret_cast<const bf8v*>(&dbT_l[l16][quad * 8]);
      bf8v ah = *reinterpret_cast<const bf8v*>(&AsT_h[t * 16 + l16][quad * 8]);
      bf8v al = *reinterpret_cast<const bf8v*>(&AsT_l[t * 16 + l16][quad * 8]);
      acc = __builtin_amdgcn_mfma_f32_16x16x32_bf16(ah, bh, acc, 0, 0, 0);
      acc = __builtin_amdgcn_mfma_f32_16x16x32_bf16(ah, bl, acc, 0, 0, 0);
      acc = __builtin_amdgcn_mfma_f32_16x16x32_bf16(al, bh, acc, 0, 0, 0);
#pragma unroll
      for (int r_ = 0; r_ < 4; ++r_)
        atomicAdd(&Yv[(t * 16 + quad * 4 + r_) * 16 + l16], acc[r_]);
    }
    gridbar();
    float rho1 = 1.f / (2.f * sigma - rho);
    float s1 = rho1 * rho, s2 = 2.f * rho1 / delta;
    rho = rho1;
#pragma unroll
    for (int m = 0; m < 2; ++m) {
      int rl = (tid >> 4) + 16 * m, c = tid & 15, gi = r0 + rl;
      float mv = atomicExch(&Yv[gi * 16 + c], 0.f);   // read + re-zero
      xr[m] += dr[m];
      rr[m] -= mv;
      float dn = s1 * dr[m] + s2 * rr[m];
      dr[m] = dn;
      short h, l; split_sh(dn, h, l);
      dbT_h[c][rl] = h; dbT_l[c][rl] = l;
    }
    __syncthreads();
  }
#pragma unroll
  for (int m = 0; m < 2; ++m) {
    int rl = (tid >> 4) + 16 * m, c = tid & 15, gi = r0 + rl;
    if (gi < NMAT) X[gi * NRHS + c] = xr[m] + dr[m];
  }
}

// ---- WK[j][d] = sum_i X[i][j] K[i][d], K = Kh+Kl --------------------------
__global__ __launch_bounds__(256) void wk_kernel(const float* __restrict__ X,
                                                 const short* __restrict__ Kh,
                                                 const short* __restrict__ Kl,
                                                 float* __restrict__ WK) {
  int idx = blockIdx.x * 256 + threadIdx.x;   // < 16*640
  int j = idx / DF;
  int d = idx - j * DF;
  float acc = 0.f;
  for (int i = 0; i < NMAT; ++i) {
    float kv = bf2f(Kh[(size_t)i * DF + d]) + bf2f(Kl[(size_t)i * DF + d]);
    acc += X[i * NRHS + j] * kv;
  }
  WK[idx] = acc;
}

// ---- logits[q][c] = -gamma * dot(FX[q], WK[c]) ----------------------------
__global__ __launch_bounds__(256) void logits_kernel(const float* __restrict__ FX,
                                                     const float* __restrict__ WK,
                                                     const float* __restrict__ gamma,
                                                     float* __restrict__ out) {
  int idx = blockIdx.x * 256 + threadIdx.x;
  int q = idx >> 4, c = idx & 15;
  const float* fr = FX + (size_t)q * DF;
  const float* wr = WK + (size_t)c * DF;
  float acc = 0.f;
  for (int d = 0; d < DF; ++d) acc += fr[d] * wr[d];
  out[idx] = -gamma[0] * acc;
}

extern "C" void kernel_launch(void* const* d_in, const int* in_sizes, int n_in,
                              void* d_out, int out_size, void* d_ws, size_t ws_size,
                              hipStream_t stream) {
  const float* S = (const float*)d_in[0];
  const float* Qm = (const float*)d_in[1];
  const float* Wb = (const float*)d_in[2];
  const float* gamma = (const float*)d_in[3];
  float* out = (float*)d_out;
  char* base = (char*)d_ws;
  float* FX    = (float*)(base);                 // 240*640*4 = 614,400
  short* Kh    = (short*)(base + 614400);        // 512,000
  short* Kl    = (short*)(base + 1126400);       // 512,000
  float* WK    = (float*)(base + 1638400);       // 40,960
  float* Xb    = (float*)(base + 1679360);       // 25,600
  unsigned* bar= (unsigned*)(base + 1704960);    // ctrl block (64 B)
  float* rq    = (float*)(base + 1704968);
  float* Y0    = (float*)(base + 1705024);       // 416*16*4 = 26,624
  float* Y1    = (float*)(base + 1731648);       // 26,624
  float* V0    = (float*)(base + 1758272);       // 416*4 = 1,664
  float* V1    = (float*)(base + 1759936);       // 1,664
  float* Acc   = (float*)(base + 1761600);       // 640*640*4 = 1,638,400
  short* Aph   = (short*)(base + 3400000);       // 416*416*2 = 346,112
  short* Apl   = (short*)(base + 3746112);       // -> total 4,092,224

  // zero ctrl + Y0/Y1 + V0/V1 + Acc (contiguous) in one memset
  hipMemsetAsync((void*)bar, 0, 64 + 26624 * 2 + 1664 * 2 + 1638400, stream);
  gemm_feat_sk<<<dim3(10, 10, KSPLIT), 256, 0, stream>>>(S, Qm, Wb, Acc);
  finalize_feat<<<1600, 256, 0, stream>>>(Acc, Kh, Kl, FX);
  gemm_aul<<<dim3(7, 7), 256, 0, stream>>>(Kh, Kl, Aph, Apl);
  solve_dist<<<GBLK, 256, 0, stream>>>(Aph, Apl, Y0, Y1, V0, V1, rq, bar, Xb);
  wk_kernel<<<40, 256, 0, stream>>>(Xb, Kh, Kl, WK);
  logits_kernel<<<15, 256, 0, stream>>>(FX, WK, gamma, out);
}

// Round 9
// 269.684 us; speedup vs baseline: 1.8829x; 1.0650x over previous
//
#include <hip/hip_runtime.h>
#include <math.h>

#define DIN 3072
#define DF 640
#define MROWS 400
#define QROWS 240
#define NMAT 400
#define PN 416          // padded A dim (13*32, 26*16)
#define NRHS 16
#define CREG 50.0f
#define PVSTEPS 6
#define CSTEPS 25       // Chebyshev: 2*q^25 ~ 3.5e-3 rel (q~0.776)
#define GBLK 13         // solve blocks; each owns 32 cols of A in LDS
#define CROWS 32
#define MTILES 28       // M = FX@K^T: 4 row-tiles x 7 col-tiles of 64

typedef __attribute__((ext_vector_type(8))) short bf8v;   // 8 bf16 (4 VGPRs)
typedef __attribute__((ext_vector_type(4))) float f32x4;  // MFMA acc

__device__ __forceinline__ short bf16_rn(float x) {
  unsigned u = __float_as_uint(x);
  u += 0x7FFFu + ((u >> 16) & 1u);
  return (short)(u >> 16);
}
__device__ __forceinline__ void split_sh(float x, short& h, short& l) {
  h = bf16_rn(x);
  float hf = __uint_as_float(((unsigned)(unsigned short)h) << 16);
  l = bf16_rn(x - hf);
}
__device__ __forceinline__ float bf2f(short h) {
  return __uint_as_float(((unsigned)(unsigned short)h) << 16);
}

// ---- transpose + split Wb(3072x640) -> Wth,Wtl [640][3072] bf16 -----------
__global__ __launch_bounds__(256) void split_wt(const float* __restrict__ Wb,
                                                short* __restrict__ H,
                                                short* __restrict__ L) {
  __shared__ float T[64][65];
  int n0 = blockIdx.x * 64;   // over DF
  int k0 = blockIdx.y * 64;   // over DIN
  int c = threadIdx.x & 63, r0 = threadIdx.x >> 6;
#pragma unroll
  for (int i = 0; i < 16; ++i) {
    int r = i * 4 + r0;
    T[r][c] = Wb[(size_t)(k0 + r) * DF + n0 + c];
  }
  __syncthreads();
#pragma unroll
  for (int i = 0; i < 16; ++i) {
    int n = i * 4 + r0;
    float x = T[c][n];              // Wb[k0+c][n0+n]
    short h, l; split_sh(x, h, l);
    size_t o = (size_t)(n0 + n) * DIN + k0 + c;
    H[o] = h; L[o] = l;
  }
}

// ---- feat: [S;Q](640x3072) @ Wb -> Kh/Kl (rows<400), FX fp32 (rows>=400) --
// 32x32 tile, ONE wave, no LDS, no barriers, no atomics. A split in-register;
// B loaded directly from pre-split Wth/Wtl. Pure streaming + MFMA.
__global__ __launch_bounds__(64) void gemm_feat(const float* __restrict__ S,
                                                const float* __restrict__ Qm,
                                                const short* __restrict__ Bh,
                                                const short* __restrict__ Bl,
                                                short* __restrict__ Kh,
                                                short* __restrict__ Kl,
                                                float* __restrict__ FX) {
  int lane = threadIdx.x;
  int l16 = lane & 15, quad = lane >> 4;
  int by = blockIdx.y, bx = blockIdx.x;   // 20 x 20
  const float* srow[2];
#pragma unroll
  for (int tm = 0; tm < 2; ++tm) {
    int row = by * 32 + tm * 16 + l16;
    srow[tm] = (row < MROWS) ? (S + (size_t)row * DIN) : (Qm + (size_t)(row - MROWS) * DIN);
  }
  const short* bto[2]; const short* blo[2];
#pragma unroll
  for (int tn = 0; tn < 2; ++tn) {
    int n = bx * 32 + tn * 16 + l16;
    bto[tn] = Bh + (size_t)n * DIN;
    blo[tn] = Bl + (size_t)n * DIN;
  }
  f32x4 acc[2][2] = {{{0,0,0,0},{0,0,0,0}},{{0,0,0,0},{0,0,0,0}}};
  for (int k0 = 0; k0 < DIN; k0 += 32) {
    int ka = k0 + quad * 8;
    bf8v ah[2], al[2], bh[2], bl[2];
#pragma unroll
    for (int tm = 0; tm < 2; ++tm) {
      float4 a0 = *reinterpret_cast<const float4*>(srow[tm] + ka);
      float4 a1 = *reinterpret_cast<const float4*>(srow[tm] + ka + 4);
      float av[8] = {a0.x, a0.y, a0.z, a0.w, a1.x, a1.y, a1.z, a1.w};
#pragma unroll
      for (int j = 0; j < 8; ++j) { short h, l; split_sh(av[j], h, l); ah[tm][j] = h; al[tm][j] = l; }
    }
#pragma unroll
    for (int tn = 0; tn < 2; ++tn) {
      bh[tn] = *reinterpret_cast<const bf8v*>(bto[tn] + ka);
      bl[tn] = *reinterpret_cast<const bf8v*>(blo[tn] + ka);
    }
#pragma unroll
    for (int tm = 0; tm < 2; ++tm)
#pragma unroll
      for (int tn = 0; tn < 2; ++tn) {
        acc[tm][tn] = __builtin_amdgcn_mfma_f32_16x16x32_bf16(ah[tm], bh[tn], acc[tm][tn], 0, 0, 0);
        acc[tm][tn] = __builtin_amdgcn_mfma_f32_16x16x32_bf16(ah[tm], bl[tn], acc[tm][tn], 0, 0, 0);
        acc[tm][tn] = __builtin_amdgcn_mfma_f32_16x16x32_bf16(al[tm], bh[tn], acc[tm][tn], 0, 0, 0);
      }
  }
#pragma unroll
  for (int tm = 0; tm < 2; ++tm)
#pragma unroll
    for (int tn = 0; tn < 2; ++tn)
#pragma unroll
      for (int r = 0; r < 4; ++r) {
        int row = by * 32 + tm * 16 + quad * 4 + r;
        int col = bx * 32 + tn * 16 + l16;
        float v = acc[tm][tn][r];
        if (row < MROWS) {
          short h, l; split_sh(v, h, l);
          Kh[(size_t)row * DF + col] = h;
          Kl[(size_t)row * DF + col] = l;
        } else {
          FX[(size_t)(row - MROWS) * DF + col] = v;
        }
      }
}

// ---- MFMA: A(416x416) = K K^T + 50 I (zero-padded), bf16 hi/lo out --------
__global__ __launch_bounds__(256) void gemm_aul(const short* __restrict__ Kh,
                                                const short* __restrict__ Kl,
                                                short* __restrict__ Aph,
                                                short* __restrict__ Apl) {
  int tid = threadIdx.x;
  int wave = tid >> 6, lane = tid & 63;
  int l16 = lane & 15, quad = lane >> 4;
  int row0 = blockIdx.y * 64 + wave * 16;
  int colBase = blockIdx.x * 64;
  bool aValid = (row0 < MROWS);
  const bf8v bzero = {0,0,0,0,0,0,0,0};
  f32x4 acc[4] = {{0,0,0,0},{0,0,0,0},{0,0,0,0},{0,0,0,0}};
  for (int k0 = 0; k0 < DF; k0 += 32) {
    int ka = k0 + quad * 8;
    bf8v ah = bzero, al = bzero;
    if (aValid) {
      size_t ao = (size_t)(row0 + l16) * DF + ka;
      ah = *reinterpret_cast<const bf8v*>(Kh + ao);
      al = *reinterpret_cast<const bf8v*>(Kl + ao);
    }
#pragma unroll
    for (int t = 0; t < 4; ++t) {
      int colt = colBase + t * 16;
      bf8v bh = bzero, bl = bzero;
      if (colt < MROWS) {
        size_t bo = (size_t)(colt + l16) * DF + ka;
        bh = *reinterpret_cast<const bf8v*>(Kh + bo);
        bl = *reinterpret_cast<const bf8v*>(Kl + bo);
      }
      acc[t] = __builtin_amdgcn_mfma_f32_16x16x32_bf16(ah, bh, acc[t], 0, 0, 0);
      acc[t] = __builtin_amdgcn_mfma_f32_16x16x32_bf16(ah, bl, acc[t], 0, 0, 0);
      acc[t] = __builtin_amdgcn_mfma_f32_16x16x32_bf16(al, bh, acc[t], 0, 0, 0);
    }
  }
  if (row0 >= PN) return;
#pragma unroll
  for (int t = 0; t < 4; ++t) {
    int colt = colBase + t * 16;
    if (colt >= PN) continue;
#pragma unroll
    for (int r = 0; r < 4; ++r) {
      int row = row0 + quad * 4 + r;
      int col = colt + l16;
      float v = acc[t][r];
      if (row == col && row < MROWS) v += CREG;
      short h, l; split_sh(v, h, l);
      size_t o = (size_t)row * PN + col;
      Aph[o] = h; Apl[o] = l;
    }
  }
}

// ---- fused: blocks 0..12 = column-split Chebyshev solve (R8 scheme);
//      blocks 13..40 = M = FX @ K^T (64x64 tiles, direct loads, no LDS).
// M is solve-independent and hides fully under the solve's ~85us.
__global__ __launch_bounds__(256) void solve_and_m(const short* __restrict__ Aph,
                                                   const short* __restrict__ Apl,
                                                   const float* __restrict__ FX,
                                                   const short* __restrict__ Kh,
                                                   const short* __restrict__ Kl,
                                                   float* __restrict__ Y0,
                                                   float* __restrict__ Y1,
                                                   float* __restrict__ V0,
                                                   float* __restrict__ V1,
                                                   float* __restrict__ rq,
                                                   unsigned* __restrict__ bar,
                                                   float* __restrict__ X,
                                                   float* __restrict__ M) {
  int tid = threadIdx.x, b = blockIdx.x;
  int wave = tid >> 6, lane = tid & 63, l16 = lane & 15, quad = lane >> 4;

  if (b >= GBLK) {
    // ================= M role: tile of FX(240x640) @ K^T(640x400) =========
    int mt = b - GBLK;             // 0..27
    int mb = mt / 7, nb = mt - (mt / 7) * 7;
    int q0 = mb * 64 + wave * 16;  // output row base for this wave
    const bf8v bzero = {0,0,0,0,0,0,0,0};
    f32x4 acc[4] = {{0,0,0,0},{0,0,0,0},{0,0,0,0},{0,0,0,0}};
    int arow = q0 + l16;
    bool aOk = (arow < QROWS);
    const float* fr = FX + (size_t)(aOk ? arow : 0) * DF;
    for (int k0 = 0; k0 < DF; k0 += 32) {
      int ka = k0 + quad * 8;
      bf8v ah = bzero, al = bzero;
      if (aOk) {
        float4 a0 = *reinterpret_cast<const float4*>(fr + ka);
        float4 a1 = *reinterpret_cast<const float4*>(fr + ka + 4);
        float av[8] = {a0.x, a0.y, a0.z, a0.w, a1.x, a1.y, a1.z, a1.w};
#pragma unroll
        for (int j = 0; j < 8; ++j) { short h, l; split_sh(av[j], h, l); ah[j] = h; al[j] = l; }
      }
#pragma unroll
      for (int t = 0; t < 4; ++t) {
        int n = nb * 64 + t * 16 + l16;
        bf8v bh = bzero, bl = bzero;
        if (n < NMAT) {
          bh = *reinterpret_cast<const bf8v*>(Kh + (size_t)n * DF + ka);
          bl = *reinterpret_cast<const bf8v*>(Kl + (size_t)n * DF + ka);
        }
        acc[t] = __builtin_amdgcn_mfma_f32_16x16x32_bf16(ah, bh, acc[t], 0, 0, 0);
        acc[t] = __builtin_amdgcn_mfma_f32_16x16x32_bf16(ah, bl, acc[t], 0, 0, 0);
        acc[t] = __builtin_amdgcn_mfma_f32_16x16x32_bf16(al, bh, acc[t], 0, 0, 0);
      }
    }
#pragma unroll
    for (int t = 0; t < 4; ++t)
#pragma unroll
      for (int r = 0; r < 4; ++r) {
        int row = q0 + quad * 4 + r;
        int col = nb * 64 + t * 16 + l16;
        if (row < QROWS && col < NMAT) M[(size_t)row * NMAT + col] = acc[t][r];
      }
    return;
  }

  // ================= solve role (R8 column-split scheme) ===================
  __shared__ short AsT_h[PN][40];   // AsT[i][jl] = A[r0+jl][i] (sym) 33.3KB
  __shared__ short AsT_l[PN][40];   // 33.3KB
  __shared__ short dbT_h[16][40];   // d B-operand [c][k_local]
  __shared__ short dbT_l[16][40];
  __shared__ float pvp[CROWS], pvc[CROWS];
  __shared__ float scal[2];
  int r0 = b * CROWS;

  for (int e = tid; e < CROWS * (PN / 8); e += 256) {
    int jl = e / (PN / 8), ic = e - (e / (PN / 8)) * (PN / 8);
    bf8v vh = *reinterpret_cast<const bf8v*>(Aph + (size_t)(r0 + jl) * PN + ic * 8);
    bf8v vl = *reinterpret_cast<const bf8v*>(Apl + (size_t)(r0 + jl) * PN + ic * 8);
#pragma unroll
    for (int u = 0; u < 8; ++u) {
      AsT_h[ic * 8 + u][jl] = vh[u];
      AsT_l[ic * 8 + u][jl] = vl[u];
    }
  }
  for (int e = tid; e < 16 * 40; e += 256) {
    (&dbT_h[0][0])[e] = 0; (&dbT_l[0][0])[e] = 0;
  }
  __syncthreads();
  if (tid < CROWS) {
    int gi = r0 + tid;
    float v = (gi < NMAT) ? (1.f + 0.125f * (float)(gi & 7)) : 0.f;
    pvc[tid] = v;
    dbT_h[0][tid] = bf16_rn(v);
  }
  __syncthreads();

  unsigned ph = 0;
  auto gridbar = [&]() {
    __syncthreads();
    ++ph;
    if (tid == 0) {
      unsigned tgt = ph * GBLK;
      __hip_atomic_fetch_add(bar, 1u, __ATOMIC_RELEASE, __HIP_MEMORY_SCOPE_AGENT);
      while (__hip_atomic_load(bar, __ATOMIC_RELAXED, __HIP_MEMORY_SCOPE_AGENT) < tgt)
        __builtin_amdgcn_s_sleep(2);
    }
    __syncthreads();
  };

  // ---- power iteration: partial y = A[:,own] @ v_own, hi only, col 0 ----
  for (int s = 0; s < PVSTEPS; ++s) {
    float* Yv = (s & 1) ? V1 : V0;
    for (int t = wave; t < 26; t += 4) {
      f32x4 acc = {0, 0, 0, 0};
      bf8v bh = *reinterpret_cast<const bf8v*>(&dbT_h[l16][quad * 8]);
      bf8v ah = *reinterpret_cast<const bf8v*>(&AsT_h[t * 16 + l16][quad * 8]);
      acc = __builtin_amdgcn_mfma_f32_16x16x32_bf16(ah, bh, acc, 0, 0, 0);
      if (l16 == 0) {
#pragma unroll
        for (int r_ = 0; r_ < 4; ++r_)
          atomicAdd(&Yv[t * 16 + quad * 4 + r_], acc[r_]);
      }
    }
    gridbar();
    if (tid < CROWS) {
      float y = atomicExch(&Yv[r0 + tid], 0.f);   // coherent read + re-zero
      float v = y * (1.f / 4096.f);
      pvp[tid] = pvc[tid];
      pvc[tid] = v;
      dbT_h[0][tid] = bf16_rn(v);
    }
    __syncthreads();
  }
  // ---- Rayleigh quotient (partial dots over own slice) ----
  if (tid == 0) {
    float n = 0.f, dd = 0.f;
    for (int u = 0; u < CROWS; ++u) { n += pvp[u] * pvc[u]; dd += pvp[u] * pvp[u]; }
    atomicAdd(&rq[0], n);
    atomicAdd(&rq[1], dd);
  }
  gridbar();
  if (tid == 0) {
    float rn = atomicAdd(&rq[0], 0.f), rd = atomicAdd(&rq[1], 0.f);
    float rqv = 4096.f * rn / rd;
    float bb = 1.25f * rqv;
    if (!(bb > 800.f)) bb = 12000.f;   // degenerate/NaN fallback
    if (bb > 100000.f) bb = 100000.f;
    scal[0] = 0.5f * (bb + CREG);      // theta
    scal[1] = 0.5f * (bb - CREG);      // delta
  }
  __syncthreads();
  float theta = scal[0], delta = scal[1];
  float sigma = theta / delta, rho = 1.f / sigma;

  // ---- Chebyshev init: thread owns (rl = tid>>4 + 16m, c = tid&15) ----
  float xr[2], rr[2], dr[2];
#pragma unroll
  for (int m = 0; m < 2; ++m) {
    int rl = (tid >> 4) + 16 * m, c = tid & 15, gi = r0 + rl;
    float pc = (gi < NMAT && (gi / 25) == c) ? 1.f : 0.f;
    xr[m] = 0.f; rr[m] = pc; dr[m] = pc / theta;
    short h, l; split_sh(dr[m], h, l);
    dbT_h[c][rl] = h; dbT_l[c][rl] = l;
  }
  __syncthreads();

  // ---- Chebyshev steps (Saad Alg 12.1); CSTEPS-1 matvecs + final add ----
  for (int k = 0; k < CSTEPS - 1; ++k) {
    float* Yv = (k & 1) ? Y1 : Y0;
    for (int t = wave; t < 26; t += 4) {
      f32x4 acc = {0, 0, 0, 0};
      bf8v bh = *reinterpret_cast<const bf8v*>(&dbT_h[l16][quad * 8]);
      bf8v bl = *reinterpret_cast<const bf8v*>(&dbT_l[l16][quad * 8]);
      bf8v ah = *reinterpret_cast<const bf8v*>(&AsT_h[t * 16 + l16][quad * 8]);
      bf8v al = *reinterpret_cast<const bf8v*>(&AsT_l[t * 16 + l16][quad * 8]);
      acc = __builtin_amdgcn_mfma_f32_16x16x32_bf16(ah, bh, acc, 0, 0, 0);
      acc = __builtin_amdgcn_mfma_f32_16x16x32_bf16(ah, bl, acc, 0, 0, 0);
      acc = __builtin_amdgcn_mfma_f32_16x16x32_bf16(al, bh, acc, 0, 0, 0);
#pragma unroll
      for (int r_ = 0; r_ < 4; ++r_)
        atomicAdd(&Yv[(t * 16 + quad * 4 + r_) * 16 + l16], acc[r_]);
    }
    gridbar();
    float rho1 = 1.f / (2.f * sigma - rho);
    float s1 = rho1 * rho, s2 = 2.f * rho1 / delta;
    rho = rho1;
#pragma unroll
    for (int m = 0; m < 2; ++m) {
      int rl = (tid >> 4) + 16 * m, c = tid & 15, gi = r0 + rl;
      float mv = atomicExch(&Yv[gi * 16 + c], 0.f);   // read + re-zero
      xr[m] += dr[m];
      rr[m] -= mv;
      float dn = s1 * dr[m] + s2 * rr[m];
      dr[m] = dn;
      short h, l; split_sh(dn, h, l);
      dbT_h[c][rl] = h; dbT_l[c][rl] = l;
    }
    __syncthreads();
  }
#pragma unroll
  for (int m = 0; m < 2; ++m) {
    int rl = (tid >> 4) + 16 * m, c = tid & 15, gi = r0 + rl;
    if (gi < NMAT) X[gi * NRHS + c] = xr[m] + dr[m];
  }
}

// ---- logits[q][c] = -gamma * sum_i M[q][i] X[i][c]  (tiny, 240x400x16) ----
__global__ __launch_bounds__(256) void logits_kernel(const float* __restrict__ M,
                                                     const float* __restrict__ X,
                                                     const float* __restrict__ gamma,
                                                     float* __restrict__ out) {
  __shared__ float Xs[NMAT * NRHS];     // 25.6 KB
  __shared__ float Ms[16][NMAT];        // 25.6 KB
  int tid = threadIdx.x;
  int q0 = blockIdx.x * 16;
  for (int e = tid; e < NMAT * NRHS; e += 256) Xs[e] = X[e];
  for (int e = tid; e < 16 * NMAT; e += 256) {
    int rl = e / NMAT, i = e - (e / NMAT) * NMAT;
    Ms[rl][i] = M[(size_t)(q0 + rl) * NMAT + i];
  }
  __syncthreads();
  int ql = tid >> 4, c = tid & 15;
  float acc = 0.f;
  for (int i = 0; i < NMAT; ++i) acc += Ms[ql][i] * Xs[i * NRHS + c];
  out[(size_t)(q0 + ql) * NRHS + c] = -gamma[0] * acc;
}

extern "C" void kernel_launch(void* const* d_in, const int* in_sizes, int n_in,
                              void* d_out, int out_size, void* d_ws, size_t ws_size,
                              hipStream_t stream) {
  const float* S = (const float*)d_in[0];
  const float* Qm = (const float*)d_in[1];
  const float* Wb = (const float*)d_in[2];
  const float* gamma = (const float*)d_in[3];
  float* out = (float*)d_out;
  char* base = (char*)d_ws;
  short* Kh   = (short*)(base);                  // 400*640*2 = 512,000
  short* Kl   = (short*)(base + 512000);         // 512,000
  float* FX   = (float*)(base + 1024000);        // 240*640*4 = 614,400
  short* Aph  = (short*)(base + 1638400);        // 416*416*2 = 346,112
  short* Apl  = (short*)(base + 1984512);        // 346,112
  float* Mm   = (float*)(base + 2330624);        // 240*400*4 = 384,000
  float* Xb   = (float*)(base + 2714624);        // 25,600
  unsigned* bar = (unsigned*)(base + 2740224);   // ctrl: bar, rq
  float* rq   = (float*)(base + 2740232);
  float* Y0   = (float*)(base + 2740288);        // 26,624
  float* Y1   = (float*)(base + 2766912);        // 26,624
  float* V0   = (float*)(base + 2793536);        // 1,664
  float* V1   = (float*)(base + 2795200);        // 1,664 -> end 2,796,864
  // Wt region (dead after gemm_feat) sits after everything: 7.9 MB
  short* Wth  = (short*)(base + 2796864);        // 640*3072*2 = 3,932,160
  short* Wtl  = (short*)(base + 6729024);        // -> end 10,661,184

  // zero ctrl + Y0/Y1 + V0/V1 (contiguous, 56,640 B)
  hipMemsetAsync((void*)bar, 0, 64 + 26624 * 2 + 1664 * 2, stream);
  split_wt<<<dim3(10, 48), 256, 0, stream>>>(Wb, Wth, Wtl);
  gemm_feat<<<dim3(20, 20), 64, 0, stream>>>(S, Qm, Wth, Wtl, Kh, Kl, FX);
  gemm_aul<<<dim3(7, 7), 256, 0, stream>>>(Kh, Kl, Aph, Apl);
  solve_and_m<<<GBLK + MTILES, 256, 0, stream>>>(Aph, Apl, FX, Kh, Kl,
                                                 Y0, Y1, V0, V1, rq, bar, Xb, Mm);
  logits_kernel<<<15, 256, 0, stream>>>(Mm, Xb, gamma, out);
}